// Round 2
// baseline (919.065 us; speedup 1.0000x reference)
//
#include <hip/hip_runtime.h>
#include <cmath>

#define H 128
#define EPS 1e-5f

typedef __attribute__((ext_vector_type(8))) __bf16 bf16x8;
typedef __attribute__((ext_vector_type(4))) float f32x4;
typedef __attribute__((ext_vector_type(4))) unsigned short u16x4;
typedef __attribute__((ext_vector_type(8))) unsigned short u16x8;

__device__ __forceinline__ float gelu_exact(float x) {
    return 0.5f * x * (1.0f + erff(x * 0.70710678118654752f));
}

__device__ __forceinline__ unsigned short f2bfu(float f) {
    __bf16 h = (__bf16)f;   // RNE fptrunc
    return __builtin_bit_cast(unsigned short, h);
}

// ---------------------------------------------------------------------------
// Preprocessing: counting sort of edges by dst.
// ---------------------------------------------------------------------------
__global__ __launch_bounds__(256) void hist_kernel(const int* __restrict__ dst,
                                                   int* __restrict__ cnt, int E)
{
    int i = blockIdx.x * blockDim.x + threadIdx.x;
    const int stride = gridDim.x * blockDim.x;
    for (; i < E; i += stride) atomicAdd(&cnt[dst[i]], 1);
}

// One block, 1024 threads. In-place turns cnt into exclusive-prefix (cursor),
// writes offs[] = exclusive prefix, offs[N] = E.
__global__ __launch_bounds__(1024) void scan_kernel(int* __restrict__ cnt,
                                                    int* __restrict__ offs,
                                                    int Nn, int E)
{
    __shared__ int part[1024];
    const int t = threadIdx.x;
    const int CH = (Nn + 1023) / 1024;
    const int base = t * CH;
    int s = 0;
    for (int i = 0; i < CH; ++i) {
        int idx = base + i;
        if (idx < Nn) s += cnt[idx];
    }
    part[t] = s;
    __syncthreads();
    for (int d = 1; d < 1024; d <<= 1) {
        int v = (t >= d) ? part[t - d] : 0;
        __syncthreads();
        part[t] += v;
        __syncthreads();
    }
    int run = (t > 0) ? part[t - 1] : 0;
    for (int i = 0; i < CH; ++i) {
        int idx = base + i;
        if (idx < Nn) {
            int c = cnt[idx];
            offs[idx] = run;
            cnt[idx] = run;   // becomes the scatter cursor
            run += c;
        }
    }
    if (t == 0) offs[Nn] = E;
}

__global__ __launch_bounds__(256) void scatter_kernel(const int* __restrict__ dst,
                                                      int* __restrict__ cur,
                                                      int* __restrict__ perm, int E)
{
    int i = blockIdx.x * blockDim.x + threadIdx.x;
    const int stride = gridDim.x * blockDim.x;
    for (; i < E; i += stride) {
        int n = dst[i];
        int p = atomicAdd(&cur[n], 1);
        perm[p] = i;
    }
}

// ---------------------------------------------------------------------------
// K1: fused edge kernel over dst-grouped edges.
// Block owns 32 output nodes; loops its contiguous edge range in 64-edge
// MFMA tiles; accumulates into an LDS f32 accumulator; one coalesced global
// write at the end. No global atomics.
// ---------------------------------------------------------------------------
__global__ __launch_bounds__(256) void edge_kernel(
    const float* __restrict__ x, const float* __restrict__ ea,
    const float* __restrict__ bases, const int* __restrict__ src,
    const int* __restrict__ dst, const float* __restrict__ W1,
    const float* __restrict__ b1, const int* __restrict__ perm,
    const int* __restrict__ offs, float* __restrict__ aggr, int Nn)
{
    __shared__ __align__(16) unsigned short alds[64 * 128];  // 16 KB
    __shared__ __align__(16) float acc[32 * 128];            // 16 KB
    __shared__ int eloc[64];
    __shared__ int dloc[64];

    const int tid = threadIdx.x;
    const int w = tid >> 6, l = tid & 63, lg = l >> 4, lr = l & 15;
    const int er = tid >> 2, q = tid & 3;

    // Preload B fragments (W1) and bias. B[k][n] = W1[n][k].
    bf16x8 bf[2][4];
    float b1v[2];
#pragma unroll
    for (int n = 0; n < 2; ++n) {
        int row = w * 32 + n * 16 + lr;
        b1v[n] = b1[row];
#pragma unroll
        for (int kk = 0; kk < 4; ++kk) {
            const float* p = W1 + row * H + kk * 32 + lg * 8;
            u16x8 t;
#pragma unroll
            for (int i = 0; i < 8; ++i) t[i] = f2bfu(p[i]);
            bf[n][kk] = __builtin_bit_cast(bf16x8, t);
        }
    }

    const int nb0 = blockIdx.x * 32;
    const int nend = (nb0 + 32 < Nn) ? nb0 + 32 : Nn;
    const int estart = offs[nb0];
    const int eend = offs[nend];

    for (int i = tid; i < 32 * 128; i += 256) acc[i] = 0.f;
    // (first __syncthreads below covers the acc-zero before any ds_add)

    for (int t0 = estart; t0 < eend; t0 += 64) {
        // ---- stage pos_e tile (64 x 128) as bf16, XOR-swizzled ----
        {
            const int idx = t0 + er;
            const int swz = (er & 7) << 3;
            if (idx < eend) {
                const int e = perm[idx];
                if (q == 0) { eloc[er] = e; dloc[er] = dst[e] - nb0; }
                const int s = src[e];
                const f32x4* pe = reinterpret_cast<const f32x4*>(ea + (long)e * H + q * 32);
                const f32x4* px = reinterpret_cast<const f32x4*>(x + (long)s * H + q * 32);
#pragma unroll
                for (int i = 0; i < 8; ++i) {
                    f32x4 a = pe[i];
                    f32x4 b = px[i];
                    u16x4 o;
                    o[0] = f2bfu(a[0] + b[0]);
                    o[1] = f2bfu(a[1] + b[1]);
                    o[2] = f2bfu(a[2] + b[2]);
                    o[3] = f2bfu(a[3] + b[3]);
                    int col = q * 32 + i * 4;
                    *reinterpret_cast<u16x4*>(&alds[er * 128 + (col ^ swz)]) = o;
                }
            } else {
                if (q == 0) { eloc[er] = 0; dloc[er] = 0; }
                u16x4 z = {0, 0, 0, 0};
#pragma unroll
                for (int i = 0; i < 8; ++i) {
                    int col = q * 32 + i * 4;
                    *reinterpret_cast<u16x4*>(&alds[er * 128 + (col ^ swz)]) = z;
                }
            }
        }
        __syncthreads();

        // ---- MFMA + epilogue into LDS accumulator ----
#pragma unroll
        for (int m = 0; m < 4; ++m) {
            const int arow = m * 16 + lr;
            const int aswz = (arow & 7) << 3;
            bf16x8 af[4];
#pragma unroll
            for (int kk = 0; kk < 4; ++kk)
                af[kk] = __builtin_bit_cast(bf16x8,
                    *reinterpret_cast<const u16x8*>(&alds[arow * 128 + ((kk * 32 + lg * 8) ^ aswz)]));
#pragma unroll
            for (int n = 0; n < 2; ++n) {
                f32x4 a4 = {0.f, 0.f, 0.f, 0.f};
#pragma unroll
                for (int kk = 0; kk < 4; ++kk)
                    a4 = __builtin_amdgcn_mfma_f32_16x16x32_bf16(af[kk], bf[n][kk], a4, 0, 0, 0);
                const int j = w * 32 + n * 16 + lr;
#pragma unroll
                for (int r = 0; r < 4; ++r) {
                    const int sl = m * 16 + lg * 4 + r;
                    const int idx = t0 + sl;
                    if (idx < eend) {
                        float z = a4[r] + b1v[n];
                        float v = gelu_exact(z) * bases[(long)eloc[sl] * H + j];
                        atomicAdd(&acc[dloc[sl] * 128 + j], v);
                    }
                }
            }
        }
        __syncthreads();
    }

    // ---- coalesced writeout ----
    {
        const int row = tid >> 3;
        const int cb = (tid & 7) * 16;
        if (nb0 + row < Nn) {
            f32x4* op = reinterpret_cast<f32x4*>(aggr + (long)(nb0 + row) * H + cb);
#pragma unroll
            for (int i = 0; i < 4; ++i)
                op[i] = *reinterpret_cast<const f32x4*>(&acc[row * 128 + cb + i * 4]);
        }
    }
}

// ---------------------------------------------------------------------------
// K2/K4: node GEMM  Y = f(A) @ W^T + bias, with fused column sum/sumsq
// epilogue for BatchNorm stats. PRE=true applies gelu(a*scale+shift) on load.
// ---------------------------------------------------------------------------
template <bool PRE>
__global__ __launch_bounds__(256) void node_gemm(
    const float* __restrict__ A, const float* __restrict__ W,
    const float* __restrict__ bias, const float* __restrict__ scl,
    const float* __restrict__ shf, float* __restrict__ Y,
    float* __restrict__ csum, float* __restrict__ cssq, int Nn)
{
    __shared__ __align__(16) unsigned short alds[64 * 128];

    const int tid = threadIdx.x;
    const int w = tid >> 6, l = tid & 63, lg = l >> 4, lr = l & 15;
    const int er = tid >> 2, q = tid & 3;
    const int r0 = blockIdx.x * 64;

    bf16x8 bf[2][4];
    float bv[2];
#pragma unroll
    for (int n = 0; n < 2; ++n) {
        int row = w * 32 + n * 16 + lr;
        bv[n] = bias[row];
#pragma unroll
        for (int kk = 0; kk < 4; ++kk) {
            const float* p = W + row * H + kk * 32 + lg * 8;
            u16x8 t;
#pragma unroll
            for (int i = 0; i < 8; ++i) t[i] = f2bfu(p[i]);
            bf[n][kk] = __builtin_bit_cast(bf16x8, t);
        }
    }

    {
        int rr = r0 + er;
        int rc = rr < Nn ? rr : Nn - 1;
        const f32x4* pa = reinterpret_cast<const f32x4*>(A + (long)rc * H + q * 32);
        const int swz = (er & 7) << 3;
#pragma unroll
        for (int i = 0; i < 8; ++i) {
            f32x4 v = pa[i];
            if constexpr (PRE) {
                f32x4 sc = *reinterpret_cast<const f32x4*>(scl + q * 32 + i * 4);
                f32x4 sh = *reinterpret_cast<const f32x4*>(shf + q * 32 + i * 4);
#pragma unroll
                for (int c = 0; c < 4; ++c) v[c] = gelu_exact(v[c] * sc[c] + sh[c]);
            }
            u16x4 o;
            o[0] = f2bfu(v[0]);
            o[1] = f2bfu(v[1]);
            o[2] = f2bfu(v[2]);
            o[3] = f2bfu(v[3]);
            int col = q * 32 + i * 4;
            *reinterpret_cast<u16x4*>(&alds[er * 128 + (col ^ swz)]) = o;
        }
    }
    __syncthreads();

    float ps[2] = {0.f, 0.f}, ps2[2] = {0.f, 0.f};
#pragma unroll
    for (int m = 0; m < 4; ++m) {
        const int arow = m * 16 + lr;
        const int aswz = (arow & 7) << 3;
        bf16x8 af[4];
#pragma unroll
        for (int kk = 0; kk < 4; ++kk)
            af[kk] = __builtin_bit_cast(bf16x8,
                *reinterpret_cast<const u16x8*>(&alds[arow * 128 + ((kk * 32 + lg * 8) ^ aswz)]));
#pragma unroll
        for (int n = 0; n < 2; ++n) {
            f32x4 a4 = {0.f, 0.f, 0.f, 0.f};
#pragma unroll
            for (int kk = 0; kk < 4; ++kk)
                a4 = __builtin_amdgcn_mfma_f32_16x16x32_bf16(af[kk], bf[n][kk], a4, 0, 0, 0);
            const int j = w * 32 + n * 16 + lr;
#pragma unroll
            for (int r = 0; r < 4; ++r) {
                int rr = r0 + m * 16 + lg * 4 + r;
                if (rr < Nn) {
                    float z = a4[r] + bv[n];
                    Y[(long)rr * H + j] = z;
                    ps[n] += z;
                    ps2[n] += z * z;
                }
            }
        }
    }
#pragma unroll
    for (int n = 0; n < 2; ++n) {
        float s = ps[n];
        s += __shfl_xor(s, 16);
        s += __shfl_xor(s, 32);
        float s2 = ps2[n];
        s2 += __shfl_xor(s2, 16);
        s2 += __shfl_xor(s2, 32);
        if (lg == 0) {
            int j = w * 32 + n * 16 + lr;
            atomicAdd(&csum[j], s);
            atomicAdd(&cssq[j], s2);
        }
    }
}

__global__ void finalize_bn(const float* __restrict__ csum, const float* __restrict__ cssq,
                            const float* __restrict__ g, const float* __restrict__ be,
                            float* __restrict__ scl, float* __restrict__ shf, float invN)
{
    int j = threadIdx.x;
    float mu = csum[j] * invN;
    float var = fmaxf(cssq[j] * invN - mu * mu, 0.f);
    float s = g[j] * rsqrtf(var + EPS);
    scl[j] = s;
    shf[j] = be[j] - mu * s;
}

__global__ __launch_bounds__(256) void final_gelu(
    const float* __restrict__ Y2, const float* __restrict__ scl,
    const float* __restrict__ shf, float* __restrict__ out, long n4)
{
    long i = (long)blockIdx.x * blockDim.x + threadIdx.x;
    const long stride = (long)gridDim.x * blockDim.x;
    for (; i < n4; i += stride) {
        f32x4 v = reinterpret_cast<const f32x4*>(Y2)[i];
        int c4 = (int)(i & 31);
        f32x4 sc = reinterpret_cast<const f32x4*>(scl)[c4];
        f32x4 sh = reinterpret_cast<const f32x4*>(shf)[c4];
        f32x4 o;
#pragma unroll
        for (int c = 0; c < 4; ++c) o[c] = gelu_exact(v[c] * sc[c] + sh[c]);
        reinterpret_cast<f32x4*>(out)[i] = o;
    }
}

extern "C" void kernel_launch(void* const* d_in, const int* in_sizes, int n_in,
                              void* d_out, int out_size, void* d_ws, size_t ws_size,
                              hipStream_t stream) {
    const float* x     = (const float*)d_in[0];
    const float* ea    = (const float*)d_in[1];
    const float* bases = (const float*)d_in[2];
    const int*   src   = (const int*)d_in[3];
    const int*   dst   = (const int*)d_in[4];
    const float* W1    = (const float*)d_in[5];
    const float* b1    = (const float*)d_in[6];
    const float* W2    = (const float*)d_in[7];
    const float* b2    = (const float*)d_in[8];
    const float* g1    = (const float*)d_in[9];
    const float* be1   = (const float*)d_in[10];
    const float* W3    = (const float*)d_in[11];
    const float* b3    = (const float*)d_in[12];
    const float* g2    = (const float*)d_in[13];
    const float* be2   = (const float*)d_in[14];

    const int N = in_sizes[0] / H;
    const int E = in_sizes[1] / H;

    float* ws   = (float*)d_ws;
    float* aggr = ws;                         // [N,H]; reused as y2 by K4
    float* y1   = ws + (size_t)N * H;         // [N,H] — overlaid by sort scratch
    float* stats = ws + (size_t)2 * N * H;    // 1024 floats
    float* sum1 = stats,        *ss1 = stats + 128;
    float* sum2 = stats + 256,  *ss2 = stats + 384;
    float* scl1 = stats + 512,  *shf1 = stats + 640;
    float* scl2 = stats + 768,  *shf2 = stats + 896;

    // Sort scratch overlays y1 (only live before node_gemm<false> runs).
    int* perm = (int*)y1;            // [E]
    int* cnt  = perm + E;            // [N]   (histogram -> cursor)
    int* offs = cnt + N;             // [N+1]

    hipMemsetAsync(cnt, 0, (size_t)N * sizeof(int), stream);
    hipMemsetAsync(stats, 0, 512 * sizeof(float), stream);

    // --- counting sort of edges by dst ---
    hist_kernel<<<2048, 256, 0, stream>>>(dst, cnt, E);
    scan_kernel<<<1, 1024, 0, stream>>>(cnt, offs, N, E);
    scatter_kernel<<<2048, 256, 0, stream>>>(dst, cnt, perm, E);

    // --- fused edge phase ---
    const int nodeblocks = (N + 31) / 32;
    edge_kernel<<<nodeblocks, 256, 0, stream>>>(x, ea, bases, src, dst, W1, b1,
                                                perm, offs, aggr, N);

    // --- node pipeline ---
    const int nblk = (N + 63) / 64;
    node_gemm<false><<<nblk, 256, 0, stream>>>(aggr, W2, b2, nullptr, nullptr, y1, sum1, ss1, N);
    finalize_bn<<<1, 128, 0, stream>>>(sum1, ss1, g1, be1, scl1, shf1, 1.0f / (float)N);
    node_gemm<true><<<nblk, 256, 0, stream>>>(y1, W3, b3, scl1, shf1, aggr, sum2, ss2, N);
    finalize_bn<<<1, 128, 0, stream>>>(sum2, ss2, g2, be2, scl2, shf2, 1.0f / (float)N);

    long n4 = (long)N * H / 4;
    final_gelu<<<2048, 256, 0, stream>>>(aggr, scl2, shf2, (float*)d_out, n4);
}

// Round 3
// 543.722 us; speedup vs baseline: 1.6903x; 1.6903x over previous
//
#include <hip/hip_runtime.h>
#include <cmath>

#define H 128
#define EPS 1e-5f

typedef __attribute__((ext_vector_type(8))) __bf16 bf16x8;
typedef __attribute__((ext_vector_type(4))) float f32x4;
typedef __attribute__((ext_vector_type(2))) float f32x2;
typedef __attribute__((ext_vector_type(4))) unsigned short u16x4;
typedef __attribute__((ext_vector_type(8))) unsigned short u16x8;

__device__ __forceinline__ float gelu_exact(float x) {
    return 0.5f * x * (1.0f + erff(x * 0.70710678118654752f));
}

__device__ __forceinline__ unsigned short f2bfu(float f) {
    __bf16 h = (__bf16)f;   // RNE fptrunc
    return __builtin_bit_cast(unsigned short, h);
}

// ---------------------------------------------------------------------------
// Preprocessing: counting sort of edges by dst -> rank[e] (position in
// dst-grouped order) and offs[n] (group starts).
// ---------------------------------------------------------------------------
__global__ __launch_bounds__(256) void hist_kernel(const int* __restrict__ dst,
                                                   int* __restrict__ cnt, int E)
{
    int i = blockIdx.x * blockDim.x + threadIdx.x;
    const int stride = gridDim.x * blockDim.x;
    for (; i < E; i += stride) atomicAdd(&cnt[dst[i]], 1);
}

__global__ __launch_bounds__(1024) void scan_kernel(int* __restrict__ cnt,
                                                    int* __restrict__ offs,
                                                    int Nn, int E)
{
    __shared__ int part[1024];
    const int t = threadIdx.x;
    const int CH = (Nn + 1023) / 1024;
    const int base = t * CH;
    int s = 0;
    for (int i = 0; i < CH; ++i) {
        int idx = base + i;
        if (idx < Nn) s += cnt[idx];
    }
    part[t] = s;
    __syncthreads();
    for (int d = 1; d < 1024; d <<= 1) {
        int v = (t >= d) ? part[t - d] : 0;
        __syncthreads();
        part[t] += v;
        __syncthreads();
    }
    int run = (t > 0) ? part[t - 1] : 0;
    for (int i = 0; i < CH; ++i) {
        int idx = base + i;
        if (idx < Nn) {
            int c = cnt[idx];
            offs[idx] = run;
            cnt[idx] = run;   // becomes the scatter cursor
            run += c;
        }
    }
    if (t == 0) offs[Nn] = E;
}

__global__ __launch_bounds__(256) void scatter_rank(const int* __restrict__ dst,
                                                    int* __restrict__ cur,
                                                    int* __restrict__ rank, int E)
{
    int i = blockIdx.x * blockDim.x + threadIdx.x;
    const int stride = gridDim.x * blockDim.x;
    for (; i < E; i += stride) {
        int n = dst[i];
        rank[i] = atomicAdd(&cur[n], 1);
    }
}

// ---------------------------------------------------------------------------
// Phase A: streaming edge MLP.
// v[e] = gelu((x[src[e]]+ea[e]) @ W1^T + b1) * bases[e], written as bf16 to
// vbuf at dst-sorted position rank[e]. All reads sequential (x gather L3).
// MFMA with SWAPPED operands: D[i][j] = sum_k W1[nbase+i][k]*pos_e[ebase+j][k]
// -> lane owns edge j = lr, 4 consecutive output cols i = lg*4+r
// -> 8 B packed store per (m,n) tile.
// ---------------------------------------------------------------------------
__global__ __launch_bounds__(256) void edge_mlp(
    const float* __restrict__ x, const float* __restrict__ ea,
    const float* __restrict__ bases, const int* __restrict__ src,
    const int* __restrict__ rank, const float* __restrict__ W1,
    const float* __restrict__ b1, unsigned short* __restrict__ vbuf,
    int E, int ntiles)
{
    __shared__ __align__(16) unsigned short alds[64 * 128];  // 16 KB
    __shared__ int rk_lds[64];

    const int tid = threadIdx.x;
    const int w = tid >> 6, l = tid & 63, lg = l >> 4, lr = l & 15;
    const int er = tid >> 2, q = tid & 3;

    // W1 fragments (A-operand): rows w*32 + n*16 + lr, k = kk*32 + lg*8 + t.
    bf16x8 wf[2][4];
    f32x4 b1v[2];
#pragma unroll
    for (int n = 0; n < 2; ++n) {
        int row = w * 32 + n * 16 + lr;
#pragma unroll
        for (int kk = 0; kk < 4; ++kk) {
            const float* p = W1 + row * H + kk * 32 + lg * 8;
            u16x8 t;
#pragma unroll
            for (int i = 0; i < 8; ++i) t[i] = f2bfu(p[i]);
            wf[n][kk] = __builtin_bit_cast(bf16x8, t);
        }
        b1v[n] = *reinterpret_cast<const f32x4*>(b1 + w * 32 + n * 16 + lg * 4);
    }

    for (int t = blockIdx.x; t < ntiles; t += gridDim.x) {
        const int e0 = t * 64;
        // ---- stage pos_e tile (64 x 128) as bf16, XOR-swizzled; rank too ----
        {
            int e = e0 + er;
            int ec = e < E ? e : E - 1;
            if (q == 0) rk_lds[er] = rank[ec];
            int s = src[ec];
            const f32x4* pe = reinterpret_cast<const f32x4*>(ea + (long)ec * H + q * 32);
            const f32x4* px = reinterpret_cast<const f32x4*>(x + (long)s * H + q * 32);
            const int swz = (er & 7) << 3;
#pragma unroll
            for (int i = 0; i < 8; ++i) {
                f32x4 a = pe[i];
                f32x4 b = px[i];
                u16x4 o;
                o[0] = f2bfu(a[0] + b[0]);
                o[1] = f2bfu(a[1] + b[1]);
                o[2] = f2bfu(a[2] + b[2]);
                o[3] = f2bfu(a[3] + b[3]);
                int col = q * 32 + i * 4;
                *reinterpret_cast<u16x4*>(&alds[er * 128 + (col ^ swz)]) = o;
            }
        }
        __syncthreads();

        // ---- MFMA + epilogue (packed scatter store) ----
#pragma unroll
        for (int m = 0; m < 4; ++m) {
            const int arow = m * 16 + lr;
            const int aswz = (arow & 7) << 3;
            bf16x8 af[4];
#pragma unroll
            for (int kk = 0; kk < 4; ++kk)
                af[kk] = __builtin_bit_cast(bf16x8,
                    *reinterpret_cast<const u16x8*>(&alds[arow * 128 + ((kk * 32 + lg * 8) ^ aswz)]));
            const int e = e0 + m * 16 + lr;
            const int rk = rk_lds[m * 16 + lr];
#pragma unroll
            for (int n = 0; n < 2; ++n) {
                f32x4 a4 = {0.f, 0.f, 0.f, 0.f};
#pragma unroll
                for (int kk = 0; kk < 4; ++kk)
                    a4 = __builtin_amdgcn_mfma_f32_16x16x32_bf16(wf[n][kk], af[kk], a4, 0, 0, 0);
                if (e < E) {
                    const int c0 = w * 32 + n * 16 + lg * 4;
                    f32x4 bs = *reinterpret_cast<const f32x4*>(bases + (long)e * H + c0);
                    u16x4 o;
#pragma unroll
                    for (int r = 0; r < 4; ++r) {
                        float z = a4[r] + b1v[n][r];
                        o[r] = f2bfu(gelu_exact(z) * bs[r]);
                    }
                    *reinterpret_cast<u16x4*>(vbuf + (size_t)rk * H + c0) = o;
                }
            }
        }
        __syncthreads();
    }
}

// ---------------------------------------------------------------------------
// Phase B: segment-sum of dst-grouped bf16 v rows. One wave per node.
// Reads are fully sequential device-wide; lane covers 2 columns (u32 load).
// ---------------------------------------------------------------------------
__global__ __launch_bounds__(256) void aggregate_kernel(
    const unsigned short* __restrict__ vbuf, const int* __restrict__ offs,
    float* __restrict__ aggr, int Nn)
{
    const int wv = threadIdx.x >> 6, lane = threadIdx.x & 63;
    const int n = blockIdx.x * 4 + wv;
    if (n >= Nn) return;
    const int lo = offs[n], hi = offs[n + 1];
    float a0 = 0.f, a1 = 0.f;
    int i = lo;
    for (; i + 1 < hi; i += 2) {
        unsigned u0 = *reinterpret_cast<const unsigned*>(vbuf + (size_t)i * H + lane * 2);
        unsigned u1 = *reinterpret_cast<const unsigned*>(vbuf + (size_t)(i + 1) * H + lane * 2);
        a0 += __builtin_bit_cast(float, u0 << 16) + __builtin_bit_cast(float, u1 << 16);
        a1 += __builtin_bit_cast(float, u0 & 0xffff0000u) + __builtin_bit_cast(float, u1 & 0xffff0000u);
    }
    if (i < hi) {
        unsigned u0 = *reinterpret_cast<const unsigned*>(vbuf + (size_t)i * H + lane * 2);
        a0 += __builtin_bit_cast(float, u0 << 16);
        a1 += __builtin_bit_cast(float, u0 & 0xffff0000u);
    }
    f32x2 o = {a0, a1};
    *reinterpret_cast<f32x2*>(aggr + (size_t)n * H + lane * 2) = o;
}

// ---------------------------------------------------------------------------
// Node GEMM  Y = f(A) @ W^T + bias, fused column sum/sumsq epilogue for BN
// stats. PRE=true applies gelu(a*scale+shift) on load.
// ---------------------------------------------------------------------------
template <bool PRE>
__global__ __launch_bounds__(256) void node_gemm(
    const float* __restrict__ A, const float* __restrict__ W,
    const float* __restrict__ bias, const float* __restrict__ scl,
    const float* __restrict__ shf, float* __restrict__ Y,
    float* __restrict__ csum, float* __restrict__ cssq, int Nn)
{
    __shared__ __align__(16) unsigned short alds[64 * 128];

    const int tid = threadIdx.x;
    const int w = tid >> 6, l = tid & 63, lg = l >> 4, lr = l & 15;
    const int er = tid >> 2, q = tid & 3;
    const int r0 = blockIdx.x * 64;

    bf16x8 bf[2][4];
    float bv[2];
#pragma unroll
    for (int n = 0; n < 2; ++n) {
        int row = w * 32 + n * 16 + lr;
        bv[n] = bias[row];
#pragma unroll
        for (int kk = 0; kk < 4; ++kk) {
            const float* p = W + row * H + kk * 32 + lg * 8;
            u16x8 t;
#pragma unroll
            for (int i = 0; i < 8; ++i) t[i] = f2bfu(p[i]);
            bf[n][kk] = __builtin_bit_cast(bf16x8, t);
        }
    }

    {
        int rr = r0 + er;
        int rc = rr < Nn ? rr : Nn - 1;
        const f32x4* pa = reinterpret_cast<const f32x4*>(A + (long)rc * H + q * 32);
        const int swz = (er & 7) << 3;
#pragma unroll
        for (int i = 0; i < 8; ++i) {
            f32x4 v = pa[i];
            if constexpr (PRE) {
                f32x4 sc = *reinterpret_cast<const f32x4*>(scl + q * 32 + i * 4);
                f32x4 sh = *reinterpret_cast<const f32x4*>(shf + q * 32 + i * 4);
#pragma unroll
                for (int c = 0; c < 4; ++c) v[c] = gelu_exact(v[c] * sc[c] + sh[c]);
            }
            u16x4 o;
            o[0] = f2bfu(v[0]);
            o[1] = f2bfu(v[1]);
            o[2] = f2bfu(v[2]);
            o[3] = f2bfu(v[3]);
            int col = q * 32 + i * 4;
            *reinterpret_cast<u16x4*>(&alds[er * 128 + (col ^ swz)]) = o;
        }
    }
    __syncthreads();

    float ps[2] = {0.f, 0.f}, ps2[2] = {0.f, 0.f};
#pragma unroll
    for (int m = 0; m < 4; ++m) {
        const int arow = m * 16 + lr;
        const int aswz = (arow & 7) << 3;
        bf16x8 af[4];
#pragma unroll
        for (int kk = 0; kk < 4; ++kk)
            af[kk] = __builtin_bit_cast(bf16x8,
                *reinterpret_cast<const u16x8*>(&alds[arow * 128 + ((kk * 32 + lg * 8) ^ aswz)]));
#pragma unroll
        for (int n = 0; n < 2; ++n) {
            f32x4 a4 = {0.f, 0.f, 0.f, 0.f};
#pragma unroll
            for (int kk = 0; kk < 4; ++kk)
                a4 = __builtin_amdgcn_mfma_f32_16x16x32_bf16(af[kk], bf[n][kk], a4, 0, 0, 0);
            const int j = w * 32 + n * 16 + lr;
#pragma unroll
            for (int r = 0; r < 4; ++r) {
                int rr = r0 + m * 16 + lg * 4 + r;
                if (rr < Nn) {
                    float z = a4[r] + bv[n];
                    Y[(long)rr * H + j] = z;
                    ps[n] += z;
                    ps2[n] += z * z;
                }
            }
        }
    }
#pragma unroll
    for (int n = 0; n < 2; ++n) {
        float s = ps[n];
        s += __shfl_xor(s, 16);
        s += __shfl_xor(s, 32);
        float s2 = ps2[n];
        s2 += __shfl_xor(s2, 16);
        s2 += __shfl_xor(s2, 32);
        if (lg == 0) {
            int j = w * 32 + n * 16 + lr;
            atomicAdd(&csum[j], s);
            atomicAdd(&cssq[j], s2);
        }
    }
}

__global__ void finalize_bn(const float* __restrict__ csum, const float* __restrict__ cssq,
                            const float* __restrict__ g, const float* __restrict__ be,
                            float* __restrict__ scl, float* __restrict__ shf, float invN)
{
    int j = threadIdx.x;
    float mu = csum[j] * invN;
    float var = fmaxf(cssq[j] * invN - mu * mu, 0.f);
    float s = g[j] * rsqrtf(var + EPS);
    scl[j] = s;
    shf[j] = be[j] - mu * s;
}

__global__ __launch_bounds__(256) void final_gelu(
    const float* __restrict__ Y2, const float* __restrict__ scl,
    const float* __restrict__ shf, float* __restrict__ out, long n4)
{
    long i = (long)blockIdx.x * blockDim.x + threadIdx.x;
    const long stride = (long)gridDim.x * blockDim.x;
    for (; i < n4; i += stride) {
        f32x4 v = reinterpret_cast<const f32x4*>(Y2)[i];
        int c4 = (int)(i & 31);
        f32x4 sc = reinterpret_cast<const f32x4*>(scl)[c4];
        f32x4 sh = reinterpret_cast<const f32x4*>(shf)[c4];
        f32x4 o;
#pragma unroll
        for (int c = 0; c < 4; ++c) o[c] = gelu_exact(v[c] * sc[c] + sh[c]);
        reinterpret_cast<f32x4*>(out)[i] = o;
    }
}

extern "C" void kernel_launch(void* const* d_in, const int* in_sizes, int n_in,
                              void* d_out, int out_size, void* d_ws, size_t ws_size,
                              hipStream_t stream) {
    const float* x     = (const float*)d_in[0];
    const float* ea    = (const float*)d_in[1];
    const float* bases = (const float*)d_in[2];
    const int*   src   = (const int*)d_in[3];
    const int*   dst   = (const int*)d_in[4];
    const float* W1    = (const float*)d_in[5];
    const float* b1    = (const float*)d_in[6];
    const float* W2    = (const float*)d_in[7];
    const float* b2    = (const float*)d_in[8];
    const float* g1    = (const float*)d_in[9];
    const float* be1   = (const float*)d_in[10];
    const float* W3    = (const float*)d_in[11];
    const float* b3    = (const float*)d_in[12];
    const float* g2    = (const float*)d_in[13];
    const float* be2   = (const float*)d_in[14];

    const int N = in_sizes[0] / H;
    const int E = in_sizes[1] / H;

    float* ws    = (float*)d_ws;
    float* aggr  = ws;                        // [N,H]; reused as y2
    float* y1    = aggr + (size_t)N * H;      // [N,H]
    float* stats = y1 + (size_t)N * H;        // 1024 floats
    float* sum1 = stats,        *ss1 = stats + 128;
    float* sum2 = stats + 256,  *ss2 = stats + 384;
    float* scl1 = stats + 512,  *shf1 = stats + 640;
    float* scl2 = stats + 768,  *shf2 = stats + 896;
    int* rank = (int*)(stats + 1024);         // [E]
    int* cnt  = rank + E;                     // [N]
    int* offs = cnt + N;                      // [N+1]
    unsigned short* vbuf = (unsigned short*)(((uintptr_t)(offs + N + 1) + 15) & ~(uintptr_t)15); // [E,H] bf16

    hipMemsetAsync(cnt, 0, (size_t)N * sizeof(int), stream);
    hipMemsetAsync(stats, 0, 512 * sizeof(float), stream);

    // --- counting sort (rank + offs) ---
    hist_kernel<<<2048, 256, 0, stream>>>(dst, cnt, E);
    scan_kernel<<<1, 1024, 0, stream>>>(cnt, offs, N, E);
    scatter_rank<<<2048, 256, 0, stream>>>(dst, cnt, rank, E);

    // --- Phase A: streaming edge MLP, scatter-write v (bf16) ---
    const int ntiles = (E + 63) / 64;
    edge_mlp<<<2500, 256, 0, stream>>>(x, ea, bases, src, rank, W1, b1, vbuf, E, ntiles);

    // --- Phase B: segment sum ---
    aggregate_kernel<<<(N + 3) / 4, 256, 0, stream>>>(vbuf, offs, aggr, N);

    // --- node pipeline ---
    const int nblk = (N + 63) / 64;
    node_gemm<false><<<nblk, 256, 0, stream>>>(aggr, W2, b2, nullptr, nullptr, y1, sum1, ss1, N);
    finalize_bn<<<1, 128, 0, stream>>>(sum1, ss1, g1, be1, scl1, shf1, 1.0f / (float)N);
    node_gemm<true><<<nblk, 256, 0, stream>>>(y1, W3, b3, scl1, shf1, aggr, sum2, ss2, N);
    finalize_bn<<<1, 128, 0, stream>>>(sum2, ss2, g2, be2, scl2, shf2, 1.0f / (float)N);

    long n4 = (long)N * H / 4;
    final_gelu<<<2048, 256, 0, stream>>>(aggr, scl2, shf2, (float*)d_out, n4);
}

// Round 4
// 511.061 us; speedup vs baseline: 1.7983x; 1.0639x over previous
//
#include <hip/hip_runtime.h>
#include <cmath>

#define H 128
#define EPS 1e-5f

typedef __attribute__((ext_vector_type(8))) __bf16 bf16x8;
typedef __attribute__((ext_vector_type(4))) float f32x4;
typedef __attribute__((ext_vector_type(2))) float f32x2;
typedef __attribute__((ext_vector_type(4))) unsigned short u16x4;
typedef __attribute__((ext_vector_type(8))) unsigned short u16x8;

__device__ __forceinline__ float gelu_exact(float x) {
    return 0.5f * x * (1.0f + erff(x * 0.70710678118654752f));
}

__device__ __forceinline__ unsigned short f2bfu(float f) {
    __bf16 h = (__bf16)f;   // RNE fptrunc
    return __builtin_bit_cast(unsigned short, h);
}

// ---------------------------------------------------------------------------
// Preprocessing: counting sort of edges by dst -> rank[e], offs[n].
// ---------------------------------------------------------------------------
__global__ __launch_bounds__(256) void hist_kernel(const int* __restrict__ dst,
                                                   int* __restrict__ cnt, int E)
{
    int i = blockIdx.x * blockDim.x + threadIdx.x;
    const int stride = gridDim.x * blockDim.x;
    for (; i < E; i += stride) atomicAdd(&cnt[dst[i]], 1);
}

__global__ __launch_bounds__(1024) void scan_kernel(int* __restrict__ cnt,
                                                    int* __restrict__ offs,
                                                    int Nn, int E)
{
    __shared__ int part[1024];
    const int t = threadIdx.x;
    const int CH = (Nn + 1023) / 1024;
    const int base = t * CH;
    int s = 0;
    for (int i = 0; i < CH; ++i) {
        int idx = base + i;
        if (idx < Nn) s += cnt[idx];
    }
    part[t] = s;
    __syncthreads();
    for (int d = 1; d < 1024; d <<= 1) {
        int v = (t >= d) ? part[t - d] : 0;
        __syncthreads();
        part[t] += v;
        __syncthreads();
    }
    int run = (t > 0) ? part[t - 1] : 0;
    for (int i = 0; i < CH; ++i) {
        int idx = base + i;
        if (idx < Nn) {
            int c = cnt[idx];
            offs[idx] = run;
            cnt[idx] = run;   // becomes the scatter cursor
            run += c;
        }
    }
    if (t == 0) offs[Nn] = E;
}

__global__ __launch_bounds__(256) void scatter_rank(const int* __restrict__ dst,
                                                    int* __restrict__ cur,
                                                    int* __restrict__ rank, int E)
{
    int i = blockIdx.x * blockDim.x + threadIdx.x;
    const int stride = gridDim.x * blockDim.x;
    for (; i < E; i += stride) {
        int n = dst[i];
        rank[i] = atomicAdd(&cur[n], 1);
    }
}

// ---------------------------------------------------------------------------
// Phase A: streaming edge MLP, software-pipelined.
// Per 64-edge tile: {ds_write(regs) -> barrier -> issue bases(t) ->
// issue prefetch(t+1) -> MFMA+epilogue}. Double-buffered LDS, ONE barrier
// per tile. v rows stored bf16 at dst-sorted position rank[e].
// ---------------------------------------------------------------------------
__global__ __launch_bounds__(256) void edge_mlp(
    const float* __restrict__ x, const float* __restrict__ ea,
    const float* __restrict__ bases, const int* __restrict__ src,
    const int* __restrict__ rank, const float* __restrict__ W1,
    const float* __restrict__ b1, unsigned short* __restrict__ vbuf,
    int E, int ntiles)
{
    __shared__ __align__(16) unsigned short alds[2][64 * 128];  // 32 KB
    __shared__ int rk_lds[2][64];

    const int tid = threadIdx.x;
    const int w = tid >> 6, l = tid & 63, lg = l >> 4, lr = l & 15;
    const int er = tid >> 2, q = tid & 3;

    // W1 fragments (A-operand): rows w*32 + n*16 + lr, k = kk*32 + lg*8 + t.
    bf16x8 wf[2][4];
    f32x4 b1v[2];
#pragma unroll
    for (int n = 0; n < 2; ++n) {
        int row = w * 32 + n * 16 + lr;
#pragma unroll
        for (int kk = 0; kk < 4; ++kk) {
            const float* p = W1 + row * H + kk * 32 + lg * 8;
            u16x8 tt;
#pragma unroll
            for (int i = 0; i < 8; ++i) tt[i] = f2bfu(p[i]);
            wf[n][kk] = __builtin_bit_cast(bf16x8, tt);
        }
        b1v[n] = *reinterpret_cast<const f32x4*>(b1 + w * 32 + n * 16 + lg * 4);
    }

    int t = blockIdx.x;
    if (t >= ntiles) return;

    // Prefetch registers for one tile.
    f32x4 pe[8], px[8];
    int rkreg;

#define ISSUE(TT)                                                              \
    {                                                                          \
        int e_ = (TT) * 64 + er;                                               \
        int ec_ = e_ < E ? e_ : E - 1;                                         \
        rkreg = rank[ec_];                                                     \
        int s_ = src[ec_];                                                     \
        const f32x4* pe_ = reinterpret_cast<const f32x4*>(ea + (long)ec_ * H + q * 32); \
        const f32x4* px_ = reinterpret_cast<const f32x4*>(x + (long)s_ * H + q * 32);   \
        _Pragma("unroll")                                                      \
        for (int i = 0; i < 8; ++i) { pe[i] = pe_[i]; px[i] = px_[i]; }        \
    }

    ISSUE(t);
    int c = 0;

    while (true) {
        // ---- write phase: convert + ds_write tile t into buf c ----
        {
            const int swz = (er & 7) << 3;
            if (q == 0) rk_lds[c][er] = rkreg;
#pragma unroll
            for (int i = 0; i < 8; ++i) {
                u16x4 o;
                o[0] = f2bfu(pe[i][0] + px[i][0]);
                o[1] = f2bfu(pe[i][1] + px[i][1]);
                o[2] = f2bfu(pe[i][2] + px[i][2]);
                o[3] = f2bfu(pe[i][3] + px[i][3]);
                int col = q * 32 + i * 4;
                *reinterpret_cast<u16x4*>(&alds[c][er * 128 + (col ^ swz)]) = o;
            }
        }
        __syncthreads();

        const int e0 = t * 64;
        const int tn = t + gridDim.x;
        const bool more = (tn < ntiles);

        // ---- issue bases loads for tile t FIRST (so their vmcnt wait
        //      doesn't drain the prefetch behind them) ----
        f32x4 bs[4][2];
#pragma unroll
        for (int m = 0; m < 4; ++m) {
            int e_ = e0 + m * 16 + lr;
            int ec_ = e_ < E ? e_ : E - 1;
            const float* bp = bases + (long)ec_ * H + w * 32 + lg * 4;
            bs[m][0] = *reinterpret_cast<const f32x4*>(bp);
            bs[m][1] = *reinterpret_cast<const f32x4*>(bp + 16);
        }

        // ---- issue prefetch for tile t+grid ----
        if (more) ISSUE(tn);

        // ---- compute tile t from buf c ----
#pragma unroll
        for (int m = 0; m < 4; ++m) {
            const int arow = m * 16 + lr;
            const int aswz = (arow & 7) << 3;
            bf16x8 af[4];
#pragma unroll
            for (int kk = 0; kk < 4; ++kk)
                af[kk] = __builtin_bit_cast(bf16x8,
                    *reinterpret_cast<const u16x8*>(&alds[c][arow * 128 + ((kk * 32 + lg * 8) ^ aswz)]));
            const int e = e0 + m * 16 + lr;
            const int rk = rk_lds[c][m * 16 + lr];
#pragma unroll
            for (int n = 0; n < 2; ++n) {
                f32x4 a4 = {0.f, 0.f, 0.f, 0.f};
#pragma unroll
                for (int kk = 0; kk < 4; ++kk)
                    a4 = __builtin_amdgcn_mfma_f32_16x16x32_bf16(wf[n][kk], af[kk], a4, 0, 0, 0);
                if (e < E) {
                    const int c0 = w * 32 + n * 16 + lg * 4;
                    u16x4 o;
#pragma unroll
                    for (int r = 0; r < 4; ++r) {
                        float z = a4[r] + b1v[n][r];
                        o[r] = f2bfu(gelu_exact(z) * bs[m][n][r]);
                    }
                    *reinterpret_cast<u16x4*>(vbuf + (size_t)rk * H + c0) = o;
                }
            }
        }

        if (!more) break;
        t = tn;
        c ^= 1;
    }
#undef ISSUE
}

// ---------------------------------------------------------------------------
// Phase B: segment-sum of dst-grouped bf16 v rows. One wave per node,
// 4-row unrolled for load concurrency.
// ---------------------------------------------------------------------------
__global__ __launch_bounds__(256) void aggregate_kernel(
    const unsigned short* __restrict__ vbuf, const int* __restrict__ offs,
    float* __restrict__ aggr, int Nn)
{
    const int wv = threadIdx.x >> 6, lane = threadIdx.x & 63;
    const int n = blockIdx.x * 4 + wv;
    if (n >= Nn) return;
    const int lo = offs[n], hi = offs[n + 1];
    float a0 = 0.f, a1 = 0.f;
    int i = lo;
    for (; i + 3 < hi; i += 4) {
        unsigned u0 = *reinterpret_cast<const unsigned*>(vbuf + (size_t)i * H + lane * 2);
        unsigned u1 = *reinterpret_cast<const unsigned*>(vbuf + (size_t)(i + 1) * H + lane * 2);
        unsigned u2 = *reinterpret_cast<const unsigned*>(vbuf + (size_t)(i + 2) * H + lane * 2);
        unsigned u3 = *reinterpret_cast<const unsigned*>(vbuf + (size_t)(i + 3) * H + lane * 2);
        a0 += __builtin_bit_cast(float, u0 << 16) + __builtin_bit_cast(float, u1 << 16)
            + __builtin_bit_cast(float, u2 << 16) + __builtin_bit_cast(float, u3 << 16);
        a1 += __builtin_bit_cast(float, u0 & 0xffff0000u) + __builtin_bit_cast(float, u1 & 0xffff0000u)
            + __builtin_bit_cast(float, u2 & 0xffff0000u) + __builtin_bit_cast(float, u3 & 0xffff0000u);
    }
    for (; i < hi; ++i) {
        unsigned u0 = *reinterpret_cast<const unsigned*>(vbuf + (size_t)i * H + lane * 2);
        a0 += __builtin_bit_cast(float, u0 << 16);
        a1 += __builtin_bit_cast(float, u0 & 0xffff0000u);
    }
    f32x2 o = {a0, a1};
    *reinterpret_cast<f32x2*>(aggr + (size_t)n * H + lane * 2) = o;
}

// ---------------------------------------------------------------------------
// Node GEMM  Y = f(A) @ W^T + bias, fused column sum/sumsq epilogue for BN
// stats. PRE=true applies gelu(a*scale+shift) on load.
// ---------------------------------------------------------------------------
template <bool PRE>
__global__ __launch_bounds__(256) void node_gemm(
    const float* __restrict__ A, const float* __restrict__ W,
    const float* __restrict__ bias, const float* __restrict__ scl,
    const float* __restrict__ shf, float* __restrict__ Y,
    float* __restrict__ csum, float* __restrict__ cssq, int Nn)
{
    __shared__ __align__(16) unsigned short alds[64 * 128];

    const int tid = threadIdx.x;
    const int w = tid >> 6, l = tid & 63, lg = l >> 4, lr = l & 15;
    const int er = tid >> 2, q = tid & 3;
    const int r0 = blockIdx.x * 64;

    bf16x8 bf[2][4];
    float bv[2];
#pragma unroll
    for (int n = 0; n < 2; ++n) {
        int row = w * 32 + n * 16 + lr;
        bv[n] = bias[row];
#pragma unroll
        for (int kk = 0; kk < 4; ++kk) {
            const float* p = W + row * H + kk * 32 + lg * 8;
            u16x8 t;
#pragma unroll
            for (int i = 0; i < 8; ++i) t[i] = f2bfu(p[i]);
            bf[n][kk] = __builtin_bit_cast(bf16x8, t);
        }
    }

    {
        int rr = r0 + er;
        int rc = rr < Nn ? rr : Nn - 1;
        const f32x4* pa = reinterpret_cast<const f32x4*>(A + (long)rc * H + q * 32);
        const int swz = (er & 7) << 3;
#pragma unroll
        for (int i = 0; i < 8; ++i) {
            f32x4 v = pa[i];
            if constexpr (PRE) {
                f32x4 sc = *reinterpret_cast<const f32x4*>(scl + q * 32 + i * 4);
                f32x4 sh = *reinterpret_cast<const f32x4*>(shf + q * 32 + i * 4);
#pragma unroll
                for (int c = 0; c < 4; ++c) v[c] = gelu_exact(v[c] * sc[c] + sh[c]);
            }
            u16x4 o;
            o[0] = f2bfu(v[0]);
            o[1] = f2bfu(v[1]);
            o[2] = f2bfu(v[2]);
            o[3] = f2bfu(v[3]);
            int col = q * 32 + i * 4;
            *reinterpret_cast<u16x4*>(&alds[er * 128 + (col ^ swz)]) = o;
        }
    }
    __syncthreads();

    float ps[2] = {0.f, 0.f}, ps2[2] = {0.f, 0.f};
#pragma unroll
    for (int m = 0; m < 4; ++m) {
        const int arow = m * 16 + lr;
        const int aswz = (arow & 7) << 3;
        bf16x8 af[4];
#pragma unroll
        for (int kk = 0; kk < 4; ++kk)
            af[kk] = __builtin_bit_cast(bf16x8,
                *reinterpret_cast<const u16x8*>(&alds[arow * 128 + ((kk * 32 + lg * 8) ^ aswz)]));
#pragma unroll
        for (int n = 0; n < 2; ++n) {
            f32x4 a4 = {0.f, 0.f, 0.f, 0.f};
#pragma unroll
            for (int kk = 0; kk < 4; ++kk)
                a4 = __builtin_amdgcn_mfma_f32_16x16x32_bf16(af[kk], bf[n][kk], a4, 0, 0, 0);
            const int j = w * 32 + n * 16 + lr;
#pragma unroll
            for (int r = 0; r < 4; ++r) {
                int rr = r0 + m * 16 + lg * 4 + r;
                if (rr < Nn) {
                    float z = a4[r] + bv[n];
                    Y[(long)rr * H + j] = z;
                    ps[n] += z;
                    ps2[n] += z * z;
                }
            }
        }
    }
#pragma unroll
    for (int n = 0; n < 2; ++n) {
        float s = ps[n];
        s += __shfl_xor(s, 16);
        s += __shfl_xor(s, 32);
        float s2 = ps2[n];
        s2 += __shfl_xor(s2, 16);
        s2 += __shfl_xor(s2, 32);
        if (lg == 0) {
            int j = w * 32 + n * 16 + lr;
            atomicAdd(&csum[j], s);
            atomicAdd(&cssq[j], s2);
        }
    }
}

__global__ void finalize_bn(const float* __restrict__ csum, const float* __restrict__ cssq,
                            const float* __restrict__ g, const float* __restrict__ be,
                            float* __restrict__ scl, float* __restrict__ shf, float invN)
{
    int j = threadIdx.x;
    float mu = csum[j] * invN;
    float var = fmaxf(cssq[j] * invN - mu * mu, 0.f);
    float s = g[j] * rsqrtf(var + EPS);
    scl[j] = s;
    shf[j] = be[j] - mu * s;
}

__global__ __launch_bounds__(256) void final_gelu(
    const float* __restrict__ Y2, const float* __restrict__ scl,
    const float* __restrict__ shf, float* __restrict__ out, long n4)
{
    long i = (long)blockIdx.x * blockDim.x + threadIdx.x;
    const long stride = (long)gridDim.x * blockDim.x;
    for (; i < n4; i += stride) {
        f32x4 v = reinterpret_cast<const f32x4*>(Y2)[i];
        int c4 = (int)(i & 31);
        f32x4 sc = reinterpret_cast<const f32x4*>(scl)[c4];
        f32x4 sh = reinterpret_cast<const f32x4*>(shf)[c4];
        f32x4 o;
#pragma unroll
        for (int c = 0; c < 4; ++c) o[c] = gelu_exact(v[c] * sc[c] + sh[c]);
        reinterpret_cast<f32x4*>(out)[i] = o;
    }
}

extern "C" void kernel_launch(void* const* d_in, const int* in_sizes, int n_in,
                              void* d_out, int out_size, void* d_ws, size_t ws_size,
                              hipStream_t stream) {
    const float* x     = (const float*)d_in[0];
    const float* ea    = (const float*)d_in[1];
    const float* bases = (const float*)d_in[2];
    const int*   src   = (const int*)d_in[3];
    const int*   dst   = (const int*)d_in[4];
    const float* W1    = (const float*)d_in[5];
    const float* b1    = (const float*)d_in[6];
    const float* W2    = (const float*)d_in[7];
    const float* b2    = (const float*)d_in[8];
    const float* g1    = (const float*)d_in[9];
    const float* be1   = (const float*)d_in[10];
    const float* W3    = (const float*)d_in[11];
    const float* b3    = (const float*)d_in[12];
    const float* g2    = (const float*)d_in[13];
    const float* be2   = (const float*)d_in[14];

    const int N = in_sizes[0] / H;
    const int E = in_sizes[1] / H;

    float* ws    = (float*)d_ws;
    float* aggr  = ws;                        // [N,H]; reused as y2
    float* y1    = aggr + (size_t)N * H;      // [N,H]
    float* stats = y1 + (size_t)N * H;        // 1024 floats
    float* sum1 = stats,        *ss1 = stats + 128;
    float* sum2 = stats + 256,  *ss2 = stats + 384;
    float* scl1 = stats + 512,  *shf1 = stats + 640;
    float* scl2 = stats + 768,  *shf2 = stats + 896;
    int* cnt  = (int*)(stats + 1024);         // [N]   (contiguous with stats for one memset)
    int* rank = cnt + N;                      // [E]
    int* offs = rank + E;                     // [N+1]
    unsigned short* vbuf = (unsigned short*)(((uintptr_t)(offs + N + 1) + 15) & ~(uintptr_t)15); // [E,H] bf16

    // one memset covers stats (1024 f32) + cnt (N ints)
    hipMemsetAsync(stats, 0, (size_t)(1024 + N) * sizeof(float), stream);

    // --- counting sort (rank + offs) ---
    hist_kernel<<<2048, 256, 0, stream>>>(dst, cnt, E);
    scan_kernel<<<1, 1024, 0, stream>>>(cnt, offs, N, E);
    scatter_rank<<<2048, 256, 0, stream>>>(dst, cnt, rank, E);

    // --- Phase A: pipelined streaming edge MLP ---
    const int ntiles = (E + 63) / 64;
    edge_mlp<<<1280, 256, 0, stream>>>(x, ea, bases, src, rank, W1, b1, vbuf, E, ntiles);

    // --- Phase B: segment sum ---
    aggregate_kernel<<<(N + 3) / 4, 256, 0, stream>>>(vbuf, offs, aggr, N);

    // --- node pipeline ---
    const int nblk = (N + 63) / 64;
    node_gemm<false><<<nblk, 256, 0, stream>>>(aggr, W2, b2, nullptr, nullptr, y1, sum1, ss1, N);
    finalize_bn<<<1, 128, 0, stream>>>(sum1, ss1, g1, be1, scl1, shf1, 1.0f / (float)N);
    node_gemm<true><<<nblk, 256, 0, stream>>>(y1, W3, b3, scl1, shf1, aggr, sum2, ss2, N);
    finalize_bn<<<1, 128, 0, stream>>>(sum2, ss2, g2, be2, scl2, shf2, 1.0f / (float)N);

    long n4 = (long)N * H / 4;
    final_gelu<<<2048, 256, 0, stream>>>(aggr, scl2, shf2, (float*)d_out, n4);
}